// Round 1
// baseline (799.758 us; speedup 1.0000x reference)
//
#include <hip/hip_runtime.h>
#include <math.h>

// TokenChoiceTopKRouter: fp32 gate GEMM (16384x4096 @ 4096x64^T) + sigmoid +
// biased top-8 + normalize + histogram, fused into one kernel.
//
// Layout: 256 blocks x 512 threads (8 waves). Block = 64 tokens. Each wave
// computes the full 64x64 (token x expert) tile over its private K/8 = 512
// slice, 8x8 register tile per lane. Cross-wave reduction + topk in epilogue.

constexpr int DIM     = 4096;
constexpr int NE      = 64;
constexpr int BM      = 64;   // tokens per block
constexpr int KG      = 8;    // k-slices == waves per block
constexpr int KSLICE  = DIM / KG;   // 512
constexpr int BK      = 16;         // k per staged chunk
constexpr int NCHUNK  = KSLICE / BK; // 32

__global__ __launch_bounds__(512, 2)
void router_kernel(const float* __restrict__ x, const float* __restrict__ w,
                   const float* __restrict__ bias,
                   float* __restrict__ out_scores, float* __restrict__ out_idx,
                   float* __restrict__ counts) {
  __shared__ float lds[16384];  // 64 KB: main loop = 8 waves x (xs 1024 + ws 1024)
                                // epilogue = 4 regions x 4096 (64x64 partials)
  const int tid  = threadIdx.x;
  const int wave = tid >> 6;
  const int lane = tid & 63;
  const int mt   = lane >> 3;   // token-group 0..7 (8 tokens each)
  const int nt   = lane & 7;    // expert-group 0..7 (8 experts each)
  const int tok0 = blockIdx.x * BM;

  float* xs  = &lds[wave * 2048];
  float* wsh = &lds[wave * 2048 + 1024];
  const int k0base = wave * KSLICE;

  float acc[8][8];
#pragma unroll
  for (int i = 0; i < 8; ++i)
#pragma unroll
    for (int j = 0; j < 8; ++j) acc[i][j] = 0.f;

  // ---- prefetch chunk 0 into registers ----
  float4 pfx[4], pfw[4];
#pragma unroll
  for (int it = 0; it < 4; ++it) {
    int f4f = it * 64 + lane;
    int row = f4f >> 2, cb = f4f & 3;
    pfx[it] = *(const float4*)&x[(tok0 + row) * DIM + k0base + cb * 4];
    pfw[it] = *(const float4*)&w[row * DIM + k0base + cb * 4];
  }

#pragma unroll 1
  for (int c = 0; c < NCHUNK; ++c) {
    // ---- write prefetched chunk to this wave's LDS region (XOR swizzled) ----
#pragma unroll
    for (int it = 0; it < 4; ++it) {
      int f4f = it * 64 + lane;
      int row = f4f >> 2, cb = f4f & 3;
      int sw  = cb ^ ((row >> 3) & 3);
      *(float4*)&xs[row * 16 + sw * 4]  = pfx[it];
      *(float4*)&wsh[row * 16 + sw * 4] = pfw[it];
    }
    // wave-internal visibility: writes from all 64 lanes complete before reads
    asm volatile("s_waitcnt lgkmcnt(0)" ::: "memory");
    __builtin_amdgcn_sched_barrier(0);

    // ---- issue next chunk's global loads (latency hidden under FMAs) ----
    if (c + 1 < NCHUNK) {
      const int k0 = k0base + (c + 1) * BK;
#pragma unroll
      for (int it = 0; it < 4; ++it) {
        int f4f = it * 64 + lane;
        int row = f4f >> 2, cb = f4f & 3;
        pfx[it] = *(const float4*)&x[(tok0 + row) * DIM + k0 + cb * 4];
        pfw[it] = *(const float4*)&w[row * DIM + k0 + cb * 4];
      }
    }

    // ---- 8x8 register-tile micro-kernel over this 16-wide k chunk ----
#pragma unroll
    for (int cb = 0; cb < 4; ++cb) {
      float4 a[8];
      const int swa = (cb ^ (mt & 3)) * 4;
      const int swb = (cb ^ (nt & 3)) * 4;
#pragma unroll
      for (int i = 0; i < 8; ++i) {
        int t = mt * 8 + i;
        a[i] = *(const float4*)&xs[t * 16 + swa];
      }
#pragma unroll
      for (int j = 0; j < 8; ++j) {
        int e = nt * 8 + j;
        float4 bv = *(const float4*)&wsh[e * 16 + swb];
#pragma unroll
        for (int i = 0; i < 8; ++i) {
          acc[i][j] = fmaf(a[i].x, bv.x, acc[i][j]);
          acc[i][j] = fmaf(a[i].y, bv.y, acc[i][j]);
          acc[i][j] = fmaf(a[i].z, bv.z, acc[i][j]);
          acc[i][j] = fmaf(a[i].w, bv.w, acc[i][j]);
        }
      }
    }
  }

  // ---- cross-wave reduction of the 8 K-slice partials (2 phases, 4 regions) ----
  __syncthreads();
  {
    float* reg = &lds[(wave & 3) * 4096];
    if (wave < 4) {
#pragma unroll
      for (int i = 0; i < 8; ++i) {
        int t = mt * 8 + i;
#pragma unroll
        for (int j = 0; j < 8; ++j) {
          int e = nt * 8 + j;
          reg[t * 64 + ((e + t) & 63)] = acc[i][j];  // rotated cols: conflict-free scans
        }
      }
    }
    __syncthreads();
    if (wave >= 4) {
#pragma unroll
      for (int i = 0; i < 8; ++i) {
        int t = mt * 8 + i;
#pragma unroll
        for (int j = 0; j < 8; ++j) {
          int e = nt * 8 + j;
          reg[t * 64 + ((e + t) & 63)] += acc[i][j];
        }
      }
    }
  }
  __syncthreads();

  // ---- fused reduce + sigmoid + biased top-8 + normalize + histogram ----
  // 64 tokens -> one thread each, spread across all 8 waves (lane%8==0).
  if ((lane & 7) == 0) {
    const int t  = wave * 8 + (lane >> 3);
    const int gt = tok0 + t;
    float key[8], sv[8];
    int   idx[8];
#pragma unroll
    for (int j = 0; j < 8; ++j) { key[j] = -1e30f; sv[j] = 0.f; idx[j] = 0; }

    for (int e = 0; e < NE; ++e) {
      int col = (e + t) & 63;
      float l = lds[t * 64 + col] + lds[4096 + t * 64 + col] +
                lds[8192 + t * 64 + col] + lds[12288 + t * 64 + col];
      float s = 1.0f / (1.0f + expf(-l));
      float k = s + bias[e];
      // bubble-insert (strict > keeps earlier i.e. lower index on ties, like lax.top_k)
      float ck = k, cv = s; int ci = e;
#pragma unroll
      for (int j = 0; j < 8; ++j) {
        bool g = ck > key[j];
        float tk = key[j], tv = sv[j]; int ti = idx[j];
        key[j] = g ? ck : tk; sv[j] = g ? cv : tv; idx[j] = g ? ci : ti;
        ck = g ? tk : ck;     cv = g ? tv : cv;    ci = g ? ti : ci;
      }
    }

    float sum = 1e-20f;
#pragma unroll
    for (int j = 0; j < 8; ++j) sum += sv[j];
    float inv = 1.0f / sum;
#pragma unroll
    for (int j = 0; j < 8; ++j) {
      out_scores[gt * 8 + j] = sv[j] * inv;
      out_idx[gt * 8 + j]    = (float)idx[j];
      atomicAdd(&counts[idx[j]], 1.0f);
    }
  }
}

extern "C" void kernel_launch(void* const* d_in, const int* in_sizes, int n_in,
                              void* d_out, int out_size, void* d_ws, size_t ws_size,
                              hipStream_t stream) {
  const float* x    = (const float*)d_in[0];
  const float* w    = (const float*)d_in[1];
  const float* bias = (const float*)d_in[2];

  const int ntok = in_sizes[0] / DIM;        // 16384
  float* out        = (float*)d_out;
  float* out_scores = out;                   // [ntok*8]
  float* out_idx    = out + ntok * 8;        // [ntok*8] (indices as float values)
  float* counts     = out + 2 * ntok * 8;    // [64]

  hipMemsetAsync(counts, 0, NE * sizeof(float), stream);
  hipLaunchKernelGGL(router_kernel, dim3(ntok / BM), dim3(512), 0, stream,
                     x, w, bias, out_scores, out_idx, counts);
}